// Round 7
// baseline (122.714 us; speedup 1.0000x reference)
//
#include <hip/hip_runtime.h>
#include <stdint.h>

// MatrixAttentionFunc: b=2, NH=8, KD=HD=32, D=256, 64x64 spatial.
// R7: apply split over d (not j) -> writes final out directly; sum_out+Pp1
//     deleted. 4 launches: prep, proj, mid, apply.
//
// ws layout (float units), total 12,746,752 fu = 51.0 MB:
//   P_v  [bh][32][4096] fp32       @ 0          ( 2,097,152)
//   Rs   [bh][h][w][i]  bf16       @ 2097152    ( 2,097,152)
//   Cs   [bh][h][b][a]  bf16       @ 4194304    ( 2,097,152)
//   Vf   [bh][j][fid][lane][8] bf16@ 6291456    ( 1,048,576)
//   Qr   [bh][w*64+h][32d] bf16    @ 7340032    ( 1,048,576)
//   Kr   "                         @ 8388608    ( 1,048,576)
//   Qc   [bh][h*64+w][32d] bf16    @ 9437184    ( 1,048,576)
//   Kc   "                         @ 10485760   ( 1,048,576)
//   Wf   [mt*8+kc][64l][8e] bf16   @ 11534336   (   163,840)  A-frag order
//   Xtf  [b][nt*8+kc][64l][8e] bf16@ 11698176   ( 1,048,576)  B-frag order

#define SCALE 0.17677669529663687f
typedef unsigned short ushort_t;
typedef __attribute__((ext_vector_type(8))) short bf16x8;
typedef __attribute__((ext_vector_type(4))) float f32x4;

__device__ __forceinline__ unsigned short f2bf(float f) {
  unsigned int b = __float_as_uint(f);
  b += 0x7fffu + ((b >> 16) & 1u);
  return (unsigned short)(b >> 16);
}
__device__ __forceinline__ float bflo(unsigned int u) { return __uint_as_float(u << 16); }
__device__ __forceinline__ float bfhi(unsigned int u) { return __uint_as_float(u & 0xffff0000u); }
__device__ __forceinline__ unsigned int pk2(float a, float b) {
  return (unsigned int)f2bf(a) | ((unsigned int)f2bf(b) << 16);
}
__device__ __forceinline__ f32x4 mfma16(bf16x8 a, bf16x8 b, f32x4 c) {
  return __builtin_amdgcn_mfma_f32_16x16x32_bf16(a, b, c, 0, 0, 0);
}
__device__ __forceinline__ void gld16(const void* g, void* l) {
  __builtin_amdgcn_global_load_lds(
      (const __attribute__((address_space(1))) unsigned int*)g,
      (__attribute__((address_space(3))) unsigned int*)l, 16, 0, 0);
}

// ---------------- prep: bid<512 -> X fp32 -> Xtf (B-frag order bf16);
//                  bid>=512 -> W fp32 -> Wf (A-frag order bf16), mt = bid-512.
__global__ __launch_bounds__(256) void prep(const float* __restrict__ x,
                                            const float* __restrict__ w,
                                            ushort_t* __restrict__ xtf,
                                            ushort_t* __restrict__ wf) {
  const int bid = blockIdx.x;
  const int t = threadIdx.x;
  if (bid < 512) {
    __shared__ float tile[128][33];
    const int b = bid >> 8, rem = bid & 255;
    const int kc = rem >> 5;              // k0 = kc*32
    const int n0 = (rem & 31) * 128;
    const float* xb = x + (size_t)b * 256 * 4096;
#pragma unroll
    for (int rep = 0; rep < 4; rep++) {
      int idx = rep * 256 + t;
      int kk = idx >> 5, nn4 = (idx & 31) * 4;
      float4 f = *(const float4*)&xb[(size_t)(kc * 32 + kk) * 4096 + n0 + nn4];
      tile[nn4 + 0][kk] = f.x; tile[nn4 + 1][kk] = f.y;
      tile[nn4 + 2][kk] = f.z; tile[nn4 + 3][kk] = f.w;
    }
    __syncthreads();
    ushort_t* xo = xtf + (size_t)b * 1048576;
#pragma unroll
    for (int rep = 0; rep < 2; rep++) {
      int idx = rep * 256 + t;
      int n = idx >> 2, k8 = (idx & 3) * 8;       // n local 0..127, k8 in {0,8,16,24}
      uint4 o;
      o.x = pk2(tile[n][k8 + 0], tile[n][k8 + 1]);
      o.y = pk2(tile[n][k8 + 2], tile[n][k8 + 3]);
      o.z = pk2(tile[n][k8 + 4], tile[n][k8 + 5]);
      o.w = pk2(tile[n][k8 + 6], tile[n][k8 + 7]);
      int nt = (n0 + n) >> 4;
      int lane = ((n0 + n) & 15) + ((k8 >> 3) << 4);
      *(uint4*)&xo[(size_t)((nt * 8 + kc) * 64 + lane) * 8] = o;
    }
  } else {
    const int mt = bid - 512;             // 0..79
    const int wv = t >> 6, l = t & 63;
#pragma unroll
    for (int s = 0; s < 2; s++) {
      int kc = wv + s * 4;
      const float* src = &w[(size_t)(mt * 16 + (l & 15)) * 256 + kc * 32 + (l >> 4) * 8];
      float4 f0 = *(const float4*)&src[0];
      float4 f1 = *(const float4*)&src[4];
      uint4 o;
      o.x = pk2(f0.x, f0.y); o.y = pk2(f0.z, f0.w);
      o.z = pk2(f1.x, f1.y); o.w = pk2(f1.z, f1.w);
      *(uint4*)&wf[(size_t)((mt * 8 + kc) * 64 + l) * 8] = o;
    }
  }
}

// ---------------- proj v3: direct-fragment MFMA GEMM. No LDS, no barriers.
__global__ __launch_bounds__(256, 4) void proj_mfma_v3(const ushort_t* __restrict__ wf,
                                                       const ushort_t* __restrict__ xtf,
                                                       ushort_t* __restrict__ Qr,
                                                       ushort_t* __restrict__ Kr,
                                                       ushort_t* __restrict__ Qc,
                                                       ushort_t* __restrict__ Kc,
                                                       float* __restrict__ P_v) {
  const int b = blockIdx.z, by = blockIdx.y, bx = blockIdx.x;
  const int m0 = by * 128, n0 = bx * 128;
  const int t = threadIdx.x, wv = t >> 6, l = t & 63;
  const int row = l & 15, quad = l >> 4;
  const int wm = wv >> 1, wn = wv & 1;
  const ushort_t* xb = xtf + (size_t)b * 1048576;

  f32x4 acc[4][4];
#pragma unroll
  for (int i = 0; i < 4; i++)
#pragma unroll
    for (int j = 0; j < 4; j++) acc[i][j] = (f32x4){0.f, 0.f, 0.f, 0.f};

  const size_t abase = (size_t)(by * 8 + wm * 4) * 4096 + l * 8;
  const size_t bbase = (size_t)(bx * 8 + wn * 4) * 4096 + l * 8;

  for (int kc = 0; kc < 8; kc++) {
    bf16x8 af[4], bfr[4];
#pragma unroll
    for (int mf = 0; mf < 4; mf++)
      af[mf] = *(const bf16x8*)&wf[abase + mf * 4096 + kc * 512];
#pragma unroll
    for (int nf = 0; nf < 4; nf++)
      bfr[nf] = *(const bf16x8*)&xb[bbase + nf * 4096 + kc * 512];
#pragma unroll
    for (int mf = 0; mf < 4; mf++)
#pragma unroll
      for (int nf = 0; nf < 4; nf++)
        acc[mf][nf] = mfma16(af[mf], bfr[nf], acc[mf][nf]);
  }

  // epilogue: m -> (H, sec, d). sec 0..3 = rq,rk,cq,ck (bf16 frag buffers);
  // sec 4 = v (fp32 P_v). All 4 regs of a group share (H, sec).
#pragma unroll
  for (int mf = 0; mf < 4; mf++) {
    int mb = m0 + wm * 64 + mf * 16 + quad * 4;
    int H = mb / 160;
    int rem = mb - H * 160;
    int sec = rem >> 5;
    int d0 = rem & 31;
    int bh = b * 8 + H;
    if (sec < 4) {
      ushort_t* base = (sec == 0) ? Qr : (sec == 1) ? Kr : (sec == 2) ? Qc : Kc;
      base += (size_t)bh * 131072;
#pragma unroll
      for (int nf = 0; nf < 4; nf++) {
        int n = n0 + wn * 64 + nf * 16 + row;
        int orow = (sec < 2) ? ((n & 63) * 64 + (n >> 6)) : n;
        uint2 o;
        o.x = pk2(acc[mf][nf][0], acc[mf][nf][1]);
        o.y = pk2(acc[mf][nf][2], acc[mf][nf][3]);
        *(uint2*)&base[(size_t)orow * 32 + d0] = o;
      }
    } else {
      float* pvb = P_v + ((size_t)bh * 32 + d0) * 4096;
#pragma unroll
      for (int nf = 0; nf < 4; nf++) {
        int n = n0 + wn * 64 + nf * 16 + row;
#pragma unroll
        for (int r = 0; r < 4; r++)
          pvb[(size_t)r * 4096 + n] = acc[mf][nf][r];
      }
    }
  }
}

// ---------------- mid: bid<512 -> scores (mode = bid>>8); bid>=512 -> vtrans.
__global__ __launch_bounds__(256) void mid(const ushort_t* __restrict__ Qr,
                                           const ushort_t* __restrict__ Kr,
                                           const ushort_t* __restrict__ Qc,
                                           const ushort_t* __restrict__ Kc,
                                           ushort_t* __restrict__ Rs,
                                           ushort_t* __restrict__ Cs,
                                           const float* __restrict__ P_v,
                                           ushort_t* __restrict__ vf) {
  __shared__ float tile[8][64][33];
  const int bid = blockIdx.x;
  const int t = threadIdx.x, wv = t >> 6, l = t & 63;
  if (bid < 512) {
    const int mode = bid >> 8;
    const int idx = bid & 255;
    const int bh = idx >> 4, gq = idx & 15;
    const int col = l & 15, quad = l >> 4;
    const int g = gq * 4 + wv;
    const ushort_t* Qb = (mode ? Qc : Qr) + (size_t)bh * 131072 + (size_t)g * 2048;
    const ushort_t* Kb = (mode ? Kc : Kr) + (size_t)bh * 131072 + (size_t)g * 2048;

    bf16x8 aq[4], bk[4];
#pragma unroll
    for (int f = 0; f < 4; f++) {
      aq[f] = *(const bf16x8*)&Qb[(size_t)(f * 16 + col) * 32 + quad * 8];
      bk[f] = *(const bf16x8*)&Kb[(size_t)(f * 16 + col) * 32 + quad * 8];
    }
    f32x4 s[4][4];
#pragma unroll
    for (int i0 = 0; i0 < 4; i0++)
#pragma unroll
      for (int j0 = 0; j0 < 4; j0++)
        s[i0][j0] = mfma16(aq[i0], bk[j0], (f32x4){0.f, 0.f, 0.f, 0.f});

    ushort_t* ob = (mode ? Cs : Rs) + (size_t)bh * 262144;
#pragma unroll
    for (int j0 = 0; j0 < 4; j0++) {
      float sv[16];
#pragma unroll
      for (int i0 = 0; i0 < 4; i0++)
#pragma unroll
        for (int r = 0; r < 4; r++) sv[i0 * 4 + r] = s[i0][j0][r] * SCALE;
      float mx = sv[0];
#pragma unroll
      for (int q = 1; q < 16; q++) mx = fmaxf(mx, sv[q]);
      mx = fmaxf(mx, __shfl_xor(mx, 16));
      mx = fmaxf(mx, __shfl_xor(mx, 32));
      float e[16], sum = 0.f;
#pragma unroll
      for (int q = 0; q < 16; q++) { e[q] = __expf(sv[q] - mx); sum += e[q]; }
      sum += __shfl_xor(sum, 16);
      sum += __shfl_xor(sum, 32);
      const float inv = 1.f / sum;
      const int j = j0 * 16 + col;
#pragma unroll
      for (int i0 = 0; i0 < 4; i0++) {
        uint2 o;
        o.x = pk2(e[i0 * 4 + 0] * inv, e[i0 * 4 + 1] * inv);
        o.y = pk2(e[i0 * 4 + 2] * inv, e[i0 * 4 + 3] * inv);
        size_t addr = mode ? ((size_t)(g * 64 + j) * 64 + i0 * 16 + quad * 4)
                           : ((size_t)(j * 64 + g) * 64 + i0 * 16 + quad * 4);
        *(uint2*)&ob[addr] = o;
      }
    }
  } else {
    const int vid = bid - 512;
    const int jc = vid & 7, bh = vid >> 3;
    const int j0 = jc * 8;
    const float* pvb = P_v + (size_t)bh * 131072;
#pragma unroll
    for (int rep = 0; rep < 8; rep++) {
      int idx = rep * 256 + t;
      int d = idx >> 6, i = idx & 63;
      float4 f0 = *(const float4*)&pvb[(size_t)d * 4096 + i * 64 + j0];
      float4 f1 = *(const float4*)&pvb[(size_t)d * 4096 + i * 64 + j0 + 4];
      tile[0][i][d] = f0.x; tile[1][i][d] = f0.y;
      tile[2][i][d] = f0.z; tile[3][i][d] = f0.w;
      tile[4][i][d] = f1.x; tile[5][i][d] = f1.y;
      tile[6][i][d] = f1.z; tile[7][i][d] = f1.w;
    }
    __syncthreads();
    ushort_t* vo = vf + (size_t)bh * 131072;
    const int fid = t >> 6;
    const int d = (fid & 1) * 16 + (l & 15);
    const int i0 = (fid >> 1) * 32 + (l >> 4) * 8;
#pragma unroll
    for (int rep = 0; rep < 8; rep++) {
      int jl = rep;
      uint4 o;
      o.x = pk2(tile[jl][i0 + 0][d], tile[jl][i0 + 1][d]);
      o.y = pk2(tile[jl][i0 + 2][d], tile[jl][i0 + 3][d]);
      o.z = pk2(tile[jl][i0 + 4][d], tile[jl][i0 + 5][d]);
      o.w = pk2(tile[jl][i0 + 6][d], tile[jl][i0 + 7][d]);
      *(uint4*)&vo[(size_t)(((j0 + jl) * 4 + fid) * 64 + l) * 8] = o;
    }
  }
}

// ---------------- apply v5: d-split. block = bh(16) x pg(16) x ds(2).
// Each block: mf = ds only (16 d's), all 64 j in 8 phases of 8, LDS dbuf 2x16KB,
// writes final out (+v residual) for its d-slice. No partials, no sum kernel.
__global__ __launch_bounds__(256, 2) void attn_apply_v5(const float* __restrict__ P_v,
                                                        const ushort_t* __restrict__ rs,
                                                        const ushort_t* __restrict__ cs,
                                                        const ushort_t* __restrict__ vf,
                                                        float* __restrict__ out) {
  __shared__ ushort_t buf[2][8192];   // 2 x 16 KB: 8 j x 2 frag-records x 1 KB
  const int bid = blockIdx.x;
  const int ds = bid & 1, pg = (bid >> 1) & 15, bh = bid >> 5;
  const int b = bh >> 3, H = bh & 7;
  const int t = threadIdx.x, wv = t >> 6, l = t & 63;
  const int row = l & 15, quad = l >> 4;
  const int h = pg * 4 + wv;
  const ushort_t* rsl = rs + (size_t)bh * 262144 + (size_t)h * 4096;   // [w][i]
  const ushort_t* csl = cs + (size_t)bh * 262144 + (size_t)h * 4096;   // [b][a]
  const ushort_t* vb = vf + (size_t)bh * 131072;

  // B-fragments (r): rf[kc][nf], full w row
  bf16x8 rf[2][4];
#pragma unroll
  for (int nf = 0; nf < 4; nf++)
#pragma unroll
    for (int kc = 0; kc < 2; kc++)
      rf[kc][nf] = *(const bf16x8*)&rsl[(size_t)(nf * 16 + row) * 64 + kc * 32 + quad * 8];

  f32x4 acc[4];
#pragma unroll
  for (int nf = 0; nf < 4; nf++) acc[nf] = (f32x4){0.f, 0.f, 0.f, 0.f};

  // stage phase 0: flat idx over (jj(8), kcl(2), lane(64)); fid = ds + 2*kcl
#pragma unroll
  for (int u = 0; u < 4; u++) {
    int idx = u * 256 + t;
    int jj = idx >> 7, kcl = (idx >> 6) & 1, ll = idx & 63;
    gld16(&vb[(size_t)((jj * 4 + ds + 2 * kcl) * 64 + ll) * 8], &buf[0][idx * 8]);
  }
  __syncthreads();

  for (int ph = 0; ph < 8; ph++) {
    const ushort_t* bcur = buf[ph & 1];
    if (ph < 7) {
#pragma unroll
      for (int u = 0; u < 4; u++) {
        int idx = u * 256 + t;
        int jj = idx >> 7, kcl = (idx >> 6) & 1, ll = idx & 63;
        gld16(&vb[(size_t)(((ph + 1) * 8 + jj) * 4 + ds + 2 * kcl) * 64 * 8 + ll * 8],
              &buf[(ph + 1) & 1][idx * 8]);
      }
    }
    float cv[8][4];
#pragma unroll
    for (int nf = 0; nf < 4; nf++) {
      uint4 u = *(const uint4*)&csl[(size_t)(nf * 16 + row) * 64 + ph * 8];
      cv[0][nf] = bflo(u.x); cv[1][nf] = bfhi(u.x);
      cv[2][nf] = bflo(u.y); cv[3][nf] = bfhi(u.y);
      cv[4][nf] = bflo(u.z); cv[5][nf] = bfhi(u.z);
      cv[6][nf] = bflo(u.w); cv[7][nf] = bfhi(u.w);
    }
#pragma unroll
    for (int jj = 0; jj < 8; jj++) {
      bf16x8 a0 = *(const bf16x8*)&bcur[((jj * 2 + 0) * 64 + l) * 8];
      bf16x8 a1 = *(const bf16x8*)&bcur[((jj * 2 + 1) * 64 + l) * 8];
#pragma unroll
      for (int nf = 0; nf < 4; nf++) {
        f32x4 tt = (f32x4){0.f, 0.f, 0.f, 0.f};
        tt = mfma16(a0, rf[0][nf], tt);
        tt = mfma16(a1, rf[1][nf], tt);
        acc[nf] += tt * cv[jj][nf];
      }
    }
    __syncthreads();   // drains vmcnt (next-phase loads) + all reads of bcur
  }

  const float* pv = P_v + (size_t)bh * 131072 + h * 64;
  float* ob = out + ((size_t)b * 256 + H * 32) * 4096 + h * 64;
#pragma unroll
  for (int nf = 0; nf < 4; nf++)
#pragma unroll
    for (int reg = 0; reg < 4; reg++) {
      int d = ds * 16 + quad * 4 + reg;
      int wc = nf * 16 + row;
      ob[(size_t)d * 4096 + wc] = acc[nf][reg] + pv[(size_t)d * 4096 + wc];
    }
}

extern "C" void kernel_launch(void* const* d_in, const int* in_sizes, int n_in,
                              void* d_out, int out_size, void* d_ws, size_t ws_size,
                              hipStream_t stream) {
  const float* x = (const float*)d_in[0];
  const float* w = (const float*)d_in[1];
  float* out = (float*)d_out;
  float* ws = (float*)d_ws;
  float* P_v = ws;                                  //  2,097,152 fu
  ushort_t* Rs  = (ushort_t*)(ws + 2097152);        //  2,097,152 fu
  ushort_t* Cs  = (ushort_t*)(ws + 4194304);        //  2,097,152 fu
  ushort_t* Vf  = (ushort_t*)(ws + 6291456);        //  1,048,576 fu
  ushort_t* Qr  = (ushort_t*)(ws + 7340032);        //  1,048,576 fu
  ushort_t* Kr  = (ushort_t*)(ws + 8388608);        //  1,048,576 fu
  ushort_t* Qc  = (ushort_t*)(ws + 9437184);        //  1,048,576 fu
  ushort_t* Kc  = (ushort_t*)(ws + 10485760);       //  1,048,576 fu
  ushort_t* Wf  = (ushort_t*)(ws + 11534336);       //    163,840 fu
  ushort_t* Xtf = (ushort_t*)(ws + 11698176);       //  1,048,576 fu

  prep<<<592, 256, 0, stream>>>(x, w, Xtf, Wf);
  proj_mfma_v3<<<dim3(32, 10, 2), 256, 0, stream>>>(Wf, Xtf, Qr, Kr, Qc, Kc, P_v);
  mid<<<640, 256, 0, stream>>>(Qr, Kr, Qc, Kc, Rs, Cs, P_v, Vf);
  attn_apply_v5<<<512, 256, 0, stream>>>(P_v, Rs, Cs, Vf, out);
}

// Round 8
// 114.942 us; speedup vs baseline: 1.0676x; 1.0676x over previous
//
#include <hip/hip_runtime.h>
#include <stdint.h>

// MatrixAttentionFunc: b=2, NH=8, KD=HD=32, D=256, 64x64 spatial.
// R8: P_v stored bf16 (P_vb); mid LDS shrunk to 34.8KB (4 blocks/CU for scores);
//     XCD swizzle bid%8==bh%8 on mid+apply; apply 4 phases of 16 j.
//
// ws layout (float units), total 11,698,176 fu = 46.8 MB:
//   P_vb [bh][32][4096] bf16       @ 0          ( 1,048,576)
//   Rs   [bh][h][w][i]  bf16       @ 1048576    ( 2,097,152)
//   Cs   [bh][h][b][a]  bf16       @ 3145728    ( 2,097,152)
//   Vf   [bh][j][fid][lane][8] bf16@ 5242880    ( 1,048,576)
//   Qr   [bh][w*64+h][32d] bf16    @ 6291456    ( 1,048,576)
//   Kr   "                         @ 7340032    ( 1,048,576)
//   Qc   [bh][h*64+w][32d] bf16    @ 8388608    ( 1,048,576)
//   Kc   "                         @ 9437184    ( 1,048,576)
//   Wf   [mt*8+kc][64l][8e] bf16   @ 10485760   (   163,840)  A-frag order
//   Xtf  [b][nt*8+kc][64l][8e] bf16@ 10649600   ( 1,048,576)  B-frag order

#define SCALE 0.17677669529663687f
typedef unsigned short ushort_t;
typedef __attribute__((ext_vector_type(8))) short bf16x8;
typedef __attribute__((ext_vector_type(4))) float f32x4;

__device__ __forceinline__ unsigned short f2bf(float f) {
  unsigned int b = __float_as_uint(f);
  b += 0x7fffu + ((b >> 16) & 1u);
  return (unsigned short)(b >> 16);
}
__device__ __forceinline__ float bflo(unsigned int u) { return __uint_as_float(u << 16); }
__device__ __forceinline__ float bfhi(unsigned int u) { return __uint_as_float(u & 0xffff0000u); }
__device__ __forceinline__ unsigned int pk2(float a, float b) {
  return (unsigned int)f2bf(a) | ((unsigned int)f2bf(b) << 16);
}
__device__ __forceinline__ f32x4 mfma16(bf16x8 a, bf16x8 b, f32x4 c) {
  return __builtin_amdgcn_mfma_f32_16x16x32_bf16(a, b, c, 0, 0, 0);
}
__device__ __forceinline__ void gld16(const void* g, void* l) {
  __builtin_amdgcn_global_load_lds(
      (const __attribute__((address_space(1))) unsigned int*)g,
      (__attribute__((address_space(3))) unsigned int*)l, 16, 0, 0);
}

// ---------------- prep: bid<512 -> X fp32 -> Xtf (B-frag order bf16);
//                  bid>=512 -> W fp32 -> Wf (A-frag order bf16), mt = bid-512.
__global__ __launch_bounds__(256) void prep(const float* __restrict__ x,
                                            const float* __restrict__ w,
                                            ushort_t* __restrict__ xtf,
                                            ushort_t* __restrict__ wf) {
  const int bid = blockIdx.x;
  const int t = threadIdx.x;
  if (bid < 512) {
    __shared__ float tile[128][33];
    const int b = bid >> 8, rem = bid & 255;
    const int kc = rem >> 5;              // k0 = kc*32
    const int n0 = (rem & 31) * 128;
    const float* xb = x + (size_t)b * 256 * 4096;
#pragma unroll
    for (int rep = 0; rep < 4; rep++) {
      int idx = rep * 256 + t;
      int kk = idx >> 5, nn4 = (idx & 31) * 4;
      float4 f = *(const float4*)&xb[(size_t)(kc * 32 + kk) * 4096 + n0 + nn4];
      tile[nn4 + 0][kk] = f.x; tile[nn4 + 1][kk] = f.y;
      tile[nn4 + 2][kk] = f.z; tile[nn4 + 3][kk] = f.w;
    }
    __syncthreads();
    ushort_t* xo = xtf + (size_t)b * 1048576;
#pragma unroll
    for (int rep = 0; rep < 2; rep++) {
      int idx = rep * 256 + t;
      int n = idx >> 2, k8 = (idx & 3) * 8;       // n local 0..127, k8 in {0,8,16,24}
      uint4 o;
      o.x = pk2(tile[n][k8 + 0], tile[n][k8 + 1]);
      o.y = pk2(tile[n][k8 + 2], tile[n][k8 + 3]);
      o.z = pk2(tile[n][k8 + 4], tile[n][k8 + 5]);
      o.w = pk2(tile[n][k8 + 6], tile[n][k8 + 7]);
      int nt = (n0 + n) >> 4;
      int lane = ((n0 + n) & 15) + ((k8 >> 3) << 4);
      *(uint4*)&xo[(size_t)((nt * 8 + kc) * 64 + lane) * 8] = o;
    }
  } else {
    const int mt = bid - 512;             // 0..79
    const int wv = t >> 6, l = t & 63;
#pragma unroll
    for (int s = 0; s < 2; s++) {
      int kc = wv + s * 4;
      const float* src = &w[(size_t)(mt * 16 + (l & 15)) * 256 + kc * 32 + (l >> 4) * 8];
      float4 f0 = *(const float4*)&src[0];
      float4 f1 = *(const float4*)&src[4];
      uint4 o;
      o.x = pk2(f0.x, f0.y); o.y = pk2(f0.z, f0.w);
      o.z = pk2(f1.x, f1.y); o.w = pk2(f1.z, f1.w);
      *(uint4*)&wf[(size_t)((mt * 8 + kc) * 64 + l) * 8] = o;
    }
  }
}

// ---------------- proj v4: direct-fragment MFMA GEMM. No LDS, no barriers.
// v-section now stored bf16 into P_vb.
__global__ __launch_bounds__(256, 4) void proj_mfma_v4(const ushort_t* __restrict__ wf,
                                                       const ushort_t* __restrict__ xtf,
                                                       ushort_t* __restrict__ Qr,
                                                       ushort_t* __restrict__ Kr,
                                                       ushort_t* __restrict__ Qc,
                                                       ushort_t* __restrict__ Kc,
                                                       ushort_t* __restrict__ P_vb) {
  const int b = blockIdx.z, by = blockIdx.y, bx = blockIdx.x;
  const int m0 = by * 128, n0 = bx * 128;
  const int t = threadIdx.x, wv = t >> 6, l = t & 63;
  const int row = l & 15, quad = l >> 4;
  const int wm = wv >> 1, wn = wv & 1;
  const ushort_t* xb = xtf + (size_t)b * 1048576;

  f32x4 acc[4][4];
#pragma unroll
  for (int i = 0; i < 4; i++)
#pragma unroll
    for (int j = 0; j < 4; j++) acc[i][j] = (f32x4){0.f, 0.f, 0.f, 0.f};

  const size_t abase = (size_t)(by * 8 + wm * 4) * 4096 + l * 8;
  const size_t bbase = (size_t)(bx * 8 + wn * 4) * 4096 + l * 8;

  for (int kc = 0; kc < 8; kc++) {
    bf16x8 af[4], bfr[4];
#pragma unroll
    for (int mf = 0; mf < 4; mf++)
      af[mf] = *(const bf16x8*)&wf[abase + mf * 4096 + kc * 512];
#pragma unroll
    for (int nf = 0; nf < 4; nf++)
      bfr[nf] = *(const bf16x8*)&xb[bbase + nf * 4096 + kc * 512];
#pragma unroll
    for (int mf = 0; mf < 4; mf++)
#pragma unroll
      for (int nf = 0; nf < 4; nf++)
        acc[mf][nf] = mfma16(af[mf], bfr[nf], acc[mf][nf]);
  }

  // epilogue: m -> (H, sec, d). sec 0..3 = rq,rk,cq,ck; sec 4 = v (bf16 P_vb).
#pragma unroll
  for (int mf = 0; mf < 4; mf++) {
    int mb = m0 + wm * 64 + mf * 16 + quad * 4;
    int H = mb / 160;
    int rem = mb - H * 160;
    int sec = rem >> 5;
    int d0 = rem & 31;
    int bh = b * 8 + H;
    if (sec < 4) {
      ushort_t* base = (sec == 0) ? Qr : (sec == 1) ? Kr : (sec == 2) ? Qc : Kc;
      base += (size_t)bh * 131072;
#pragma unroll
      for (int nf = 0; nf < 4; nf++) {
        int n = n0 + wn * 64 + nf * 16 + row;
        int orow = (sec < 2) ? ((n & 63) * 64 + (n >> 6)) : n;
        uint2 o;
        o.x = pk2(acc[mf][nf][0], acc[mf][nf][1]);
        o.y = pk2(acc[mf][nf][2], acc[mf][nf][3]);
        *(uint2*)&base[(size_t)orow * 32 + d0] = o;
      }
    } else {
      ushort_t* pvb = P_vb + ((size_t)bh * 32 + d0) * 4096;
#pragma unroll
      for (int nf = 0; nf < 4; nf++) {
        int n = n0 + wn * 64 + nf * 16 + row;
#pragma unroll
        for (int r = 0; r < 4; r++)
          pvb[(size_t)r * 4096 + n] = f2bf(acc[mf][nf][r]);
      }
    }
  }
}

// ---------------- mid: bid<512 -> scores; bid>=512 -> vtrans (bf16 transpose).
// XCD swizzle: bid%8 == bh%8 for both halves.
__global__ __launch_bounds__(256) void mid(const ushort_t* __restrict__ Qr,
                                           const ushort_t* __restrict__ Kr,
                                           const ushort_t* __restrict__ Qc,
                                           const ushort_t* __restrict__ Kc,
                                           ushort_t* __restrict__ Rs,
                                           ushort_t* __restrict__ Cs,
                                           const ushort_t* __restrict__ P_vb,
                                           ushort_t* __restrict__ vf) {
  __shared__ ushort_t tile[8][64][34];   // 34,816 B -> 4 blocks/CU
  const int bid = blockIdx.x;
  const int t = threadIdx.x, wv = t >> 6, l = t & 63;
  if (bid < 512) {
    // decode: xr=bh&7 in low bits so bid%8 == bh%8
    const int xr = bid & 7, rest = bid >> 3;
    const int gq = rest & 15, mode = (rest >> 4) & 1, bhHi = rest >> 5;
    const int bh = bhHi * 8 + xr;
    const int col = l & 15, quad = l >> 4;
    const int g = gq * 4 + wv;
    const ushort_t* Qb = (mode ? Qc : Qr) + (size_t)bh * 131072 + (size_t)g * 2048;
    const ushort_t* Kb = (mode ? Kc : Kr) + (size_t)bh * 131072 + (size_t)g * 2048;

    bf16x8 aq[4], bk[4];
#pragma unroll
    for (int f = 0; f < 4; f++) {
      aq[f] = *(const bf16x8*)&Qb[(size_t)(f * 16 + col) * 32 + quad * 8];
      bk[f] = *(const bf16x8*)&Kb[(size_t)(f * 16 + col) * 32 + quad * 8];
    }
    f32x4 s[4][4];
#pragma unroll
    for (int i0 = 0; i0 < 4; i0++)
#pragma unroll
      for (int j0 = 0; j0 < 4; j0++)
        s[i0][j0] = mfma16(aq[i0], bk[j0], (f32x4){0.f, 0.f, 0.f, 0.f});

    ushort_t* ob = (mode ? Cs : Rs) + (size_t)bh * 262144;
#pragma unroll
    for (int j0 = 0; j0 < 4; j0++) {
      float sv[16];
#pragma unroll
      for (int i0 = 0; i0 < 4; i0++)
#pragma unroll
        for (int r = 0; r < 4; r++) sv[i0 * 4 + r] = s[i0][j0][r] * SCALE;
      float mx = sv[0];
#pragma unroll
      for (int q = 1; q < 16; q++) mx = fmaxf(mx, sv[q]);
      mx = fmaxf(mx, __shfl_xor(mx, 16));
      mx = fmaxf(mx, __shfl_xor(mx, 32));
      float e[16], sum = 0.f;
#pragma unroll
      for (int q = 0; q < 16; q++) { e[q] = __expf(sv[q] - mx); sum += e[q]; }
      sum += __shfl_xor(sum, 16);
      sum += __shfl_xor(sum, 32);
      const float inv = 1.f / sum;
      const int j = j0 * 16 + col;
#pragma unroll
      for (int i0 = 0; i0 < 4; i0++) {
        uint2 o;
        o.x = pk2(e[i0 * 4 + 0] * inv, e[i0 * 4 + 1] * inv);
        o.y = pk2(e[i0 * 4 + 2] * inv, e[i0 * 4 + 3] * inv);
        size_t addr = mode ? ((size_t)(g * 64 + j) * 64 + i0 * 16 + quad * 4)
                           : ((size_t)(j * 64 + g) * 64 + i0 * 16 + quad * 4);
        *(uint2*)&ob[addr] = o;
      }
    }
  } else {
    // vtrans: P_vb[bh][d][i*64+j] bf16 -> Vf[bh][j][fid][lane][8e] bf16
    const int v = bid - 512;              // 0..127
    const int xr = v & 7, jc = (v >> 3) & 7, bhHi = v >> 6;
    const int bh = bhHi * 8 + xr;
    const int j0 = jc * 8;
    const ushort_t* pvb = P_vb + (size_t)bh * 131072;
#pragma unroll
    for (int rep = 0; rep < 8; rep++) {
      int idx = rep * 256 + t;
      int d = idx >> 6, i = idx & 63;
      uint4 u = *(const uint4*)&pvb[(size_t)d * 4096 + i * 64 + j0];  // j0..j0+7
      tile[0][i][d] = (ushort_t)(u.x & 0xffff);
      tile[1][i][d] = (ushort_t)(u.x >> 16);
      tile[2][i][d] = (ushort_t)(u.y & 0xffff);
      tile[3][i][d] = (ushort_t)(u.y >> 16);
      tile[4][i][d] = (ushort_t)(u.z & 0xffff);
      tile[5][i][d] = (ushort_t)(u.z >> 16);
      tile[6][i][d] = (ushort_t)(u.w & 0xffff);
      tile[7][i][d] = (ushort_t)(u.w >> 16);
    }
    __syncthreads();
    ushort_t* vo = vf + (size_t)bh * 131072;
    const int fid = t >> 6;
    const int d = (fid & 1) * 16 + (l & 15);
    const int i0 = (fid >> 1) * 32 + (l >> 4) * 8;
#pragma unroll
    for (int jl = 0; jl < 8; jl++) {
      uint4 o;
      o.x = (unsigned int)tile[jl][i0 + 0][d] | ((unsigned int)tile[jl][i0 + 1][d] << 16);
      o.y = (unsigned int)tile[jl][i0 + 2][d] | ((unsigned int)tile[jl][i0 + 3][d] << 16);
      o.z = (unsigned int)tile[jl][i0 + 4][d] | ((unsigned int)tile[jl][i0 + 5][d] << 16);
      o.w = (unsigned int)tile[jl][i0 + 6][d] | ((unsigned int)tile[jl][i0 + 7][d] << 16);
      *(uint4*)&vo[(size_t)(((j0 + jl) * 4 + fid) * 64 + l) * 8] = o;
    }
  }
}

// ---------------- apply v6: d-split, 4 phases of 16 j, LDS dbuf 2x32KB,
// XCD swizzle bid%8 == bh%8. Writes final out (+bf16 v residual).
__global__ __launch_bounds__(256, 2) void attn_apply_v6(const ushort_t* __restrict__ P_vb,
                                                        const ushort_t* __restrict__ rs,
                                                        const ushort_t* __restrict__ cs,
                                                        const ushort_t* __restrict__ vf,
                                                        float* __restrict__ out) {
  __shared__ ushort_t buf[2][16384];   // 2 x 32 KB: 16 j x 2 rec x 1 KB
  const int bid = blockIdx.x;
  const int xr = bid & 7, rest = bid >> 3;
  const int ds = rest & 1, pg = (rest >> 1) & 15, bhHi = rest >> 5;
  const int bh = bhHi * 8 + xr;
  const int b = bh >> 3, H = bh & 7;
  const int t = threadIdx.x, wv = t >> 6, l = t & 63;
  const int row = l & 15, quad = l >> 4;
  const int h = pg * 4 + wv;
  const ushort_t* rsl = rs + (size_t)bh * 262144 + (size_t)h * 4096;   // [w][i]
  const ushort_t* csl = cs + (size_t)bh * 262144 + (size_t)h * 4096;   // [b][a]
  const ushort_t* vb = vf + (size_t)bh * 131072;

  // B-fragments (r): rf[kc][nf]
  bf16x8 rf[2][4];
#pragma unroll
  for (int nf = 0; nf < 4; nf++)
#pragma unroll
    for (int kc = 0; kc < 2; kc++)
      rf[kc][nf] = *(const bf16x8*)&rsl[(size_t)(nf * 16 + row) * 64 + kc * 32 + quad * 8];

  f32x4 acc[4];
#pragma unroll
  for (int nf = 0; nf < 4; nf++) acc[nf] = (f32x4){0.f, 0.f, 0.f, 0.f};

  // stage phase 0: idx over (jj(16), kcl(2), lane(64)); fid = ds + 2*kcl
#pragma unroll
  for (int u = 0; u < 8; u++) {
    int idx = u * 256 + t;
    int jj = idx >> 7, kcl = (idx >> 6) & 1, ll = idx & 63;
    gld16(&vb[(size_t)((jj * 4 + ds + 2 * kcl) * 64 + ll) * 8], &buf[0][idx * 8]);
  }
  __syncthreads();

  for (int ph = 0; ph < 4; ph++) {
    const ushort_t* bcur = buf[ph & 1];
    if (ph < 3) {
#pragma unroll
      for (int u = 0; u < 8; u++) {
        int idx = u * 256 + t;
        int jj = idx >> 7, kcl = (idx >> 6) & 1, ll = idx & 63;
        gld16(&vb[(size_t)((((ph + 1) * 16 + jj) * 4 + ds + 2 * kcl) * 64 + ll) * 8],
              &buf[(ph + 1) & 1][idx * 8]);
      }
    }
    float cv[16][4];
#pragma unroll
    for (int nf = 0; nf < 4; nf++) {
      uint4 u0 = *(const uint4*)&csl[(size_t)(nf * 16 + row) * 64 + ph * 16];
      uint4 u1 = *(const uint4*)&csl[(size_t)(nf * 16 + row) * 64 + ph * 16 + 8];
      cv[0][nf] = bflo(u0.x);  cv[1][nf] = bfhi(u0.x);
      cv[2][nf] = bflo(u0.y);  cv[3][nf] = bfhi(u0.y);
      cv[4][nf] = bflo(u0.z);  cv[5][nf] = bfhi(u0.z);
      cv[6][nf] = bflo(u0.w);  cv[7][nf] = bfhi(u0.w);
      cv[8][nf] = bflo(u1.x);  cv[9][nf] = bfhi(u1.x);
      cv[10][nf] = bflo(u1.y); cv[11][nf] = bfhi(u1.y);
      cv[12][nf] = bflo(u1.z); cv[13][nf] = bfhi(u1.z);
      cv[14][nf] = bflo(u1.w); cv[15][nf] = bfhi(u1.w);
    }
#pragma unroll
    for (int jj = 0; jj < 16; jj++) {
      bf16x8 a0 = *(const bf16x8*)&bcur[((jj * 2 + 0) * 64 + l) * 8];
      bf16x8 a1 = *(const bf16x8*)&bcur[((jj * 2 + 1) * 64 + l) * 8];
#pragma unroll
      for (int nf = 0; nf < 4; nf++) {
        f32x4 tt = (f32x4){0.f, 0.f, 0.f, 0.f};
        tt = mfma16(a0, rf[0][nf], tt);
        tt = mfma16(a1, rf[1][nf], tt);
        acc[nf] += tt * cv[jj][nf];
      }
    }
    __syncthreads();   // drains vmcnt (next-phase loads) + all reads of bcur
  }

  const ushort_t* pv = P_vb + (size_t)bh * 131072 + h * 64;
  float* ob = out + ((size_t)b * 256 + H * 32) * 4096 + h * 64;
#pragma unroll
  for (int nf = 0; nf < 4; nf++)
#pragma unroll
    for (int reg = 0; reg < 4; reg++) {
      int d = ds * 16 + quad * 4 + reg;
      int wc = nf * 16 + row;
      ob[(size_t)d * 4096 + wc] =
          acc[nf][reg] + bflo((unsigned int)pv[(size_t)d * 4096 + wc]);
    }
}

extern "C" void kernel_launch(void* const* d_in, const int* in_sizes, int n_in,
                              void* d_out, int out_size, void* d_ws, size_t ws_size,
                              hipStream_t stream) {
  const float* x = (const float*)d_in[0];
  const float* w = (const float*)d_in[1];
  float* out = (float*)d_out;
  float* ws = (float*)d_ws;
  ushort_t* P_vb = (ushort_t*)ws;                   //  1,048,576 fu
  ushort_t* Rs  = (ushort_t*)(ws + 1048576);        //  2,097,152 fu
  ushort_t* Cs  = (ushort_t*)(ws + 3145728);        //  2,097,152 fu
  ushort_t* Vf  = (ushort_t*)(ws + 5242880);        //  1,048,576 fu
  ushort_t* Qr  = (ushort_t*)(ws + 6291456);        //  1,048,576 fu
  ushort_t* Kr  = (ushort_t*)(ws + 7340032);        //  1,048,576 fu
  ushort_t* Qc  = (ushort_t*)(ws + 8388608);        //  1,048,576 fu
  ushort_t* Kc  = (ushort_t*)(ws + 9437184);        //  1,048,576 fu
  ushort_t* Wf  = (ushort_t*)(ws + 10485760);       //    163,840 fu
  ushort_t* Xtf = (ushort_t*)(ws + 10649600);       //  1,048,576 fu

  prep<<<592, 256, 0, stream>>>(x, w, Xtf, Wf);
  proj_mfma_v4<<<dim3(32, 10, 2), 256, 0, stream>>>(Wf, Xtf, Qr, Kr, Qc, Kc, P_vb);
  mid<<<640, 256, 0, stream>>>(Qr, Kr, Qc, Kc, Rs, Cs, P_vb, Vf);
  attn_apply_v6<<<512, 256, 0, stream>>>(P_vb, Rs, Cs, Vf, out);
}